// Round 8
// baseline (287.935 us; speedup 1.0000x reference)
//
#include <hip/hip_runtime.h>

#define N_NODES 100000
#define D_SRC 128
#define D_OUT 256
#define K_DIM 256   // D_DST + D_SRC
#define CAP 32      // bucket capacity per node (Poisson(6): P(deg>32) ~ 1e-15)
#define OVF_CAP 2048

typedef __attribute__((ext_vector_type(8))) short short8;
typedef __attribute__((ext_vector_type(4))) float float4v;
typedef __attribute__((ext_vector_type(4))) unsigned int uint4v;

__device__ inline unsigned short f2bf(float f) {
    unsigned int u = __float_as_uint(f);
    u += 0x7FFF + ((u >> 16) & 1);   // round-to-nearest-even
    return (unsigned short)(u >> 16);
}
__device__ inline float bf_lo(unsigned int u) { return __uint_as_float(u << 16); }
__device__ inline float bf_hi(unsigned int u) { return __uint_as_float(u & 0xFFFF0000u); }

// ---------------------------------------------------------------------------
// Kernel 1 (fused prep + bucket): bucket blocks FIRST so their long-latency
// atomics launch at t=0; the streaming pack blocks backfill the CUs and hide
// the atomic stalls (bucket alone was 60us at 0.3% VALUBusy in round 6).
//   blocks [0, nb)            : bucket, 1 edge/thread (single atomic chain)
//   blocks [nb, nb+12500)     : x_src fp32 -> bf16 linear pack (xsb)
//   blocks [.., +6250)        : x_dst fp32 -> bf16 MFMA-fragment pack (xdsw)
//   blocks [.., +32)          : W fp32 -> bf16 MFMA-fragment pack (wsw)
// deg/ovf_cnt zeroing moved to a 400KB hipMemsetAsync before this launch.
// ---------------------------------------------------------------------------
#define PREP_SRC_BLOCKS 12500              // N*128/4 float4 / 256
#define PREP_DST_BLOCKS 6250               // N*16 threads / 256
#define PREP_W_BLOCKS   32                 // 256*256/8 / 256

__global__ __launch_bounds__(256) void prep_kernel(
    const float* __restrict__ x_src,
    const float* __restrict__ x_dst,
    const float* __restrict__ W,
    const int*   __restrict__ ei,      // [2, E]
    unsigned short* __restrict__ xsb,
    unsigned short* __restrict__ xdsw,
    unsigned short* __restrict__ wsw,
    int* __restrict__ deg,             // pre-zeroed by memset
    int* __restrict__ ovf_cnt,         // pre-zeroed by memset
    int* __restrict__ ovf,
    int* __restrict__ bucket,
    int n_edges, int nb_bucket)
{
    int b = blockIdx.x;
    if (b < nb_bucket) {
        // ---- bucket: 1 edge/thread, one atomic latency exposure ----
        int e = b * 256 + threadIdx.x;
        if (e < n_edges) {
            int s = ei[e];
            int d = ei[n_edges + e];
            int pos = atomicAdd(deg + d, 1);
            if (pos < CAP) {
                bucket[(size_t)d * CAP + pos] = s;
            } else {
                int o = atomicAdd(ovf_cnt, 1);
                if (o < OVF_CAP) { ovf[2 * o] = s; ovf[2 * o + 1] = d; }
            }
        }
        return;
    }
    b -= nb_bucket;
    if (b < PREP_SRC_BLOCKS) {
        int i = b * 256 + threadIdx.x;
        float4 v = ((const float4*)x_src)[i];
        ushort4 o;
        o.x = f2bf(v.x); o.y = f2bf(v.y); o.z = f2bf(v.z); o.w = f2bf(v.w);
        ((ushort4*)xsb)[i] = o;
    } else if (b < PREP_SRC_BLOCKS + PREP_DST_BLOCKS) {
        // granule ((r>>4)*4 + kc)*64 + (r&15) + 16*sub  <- x_dst[r][kc*32+sub*8+j]
        int t = (b - PREP_SRC_BLOCKS) * 256 + threadIdx.x;
        int r = t >> 4;
        int g = t & 15;
        const float4* p = (const float4*)(x_dst + (size_t)r * 128 + g * 8);
        float4 v0 = p[0], v1 = p[1];
        union { unsigned short s[8]; short8 v; } pk;
        pk.s[0] = f2bf(v0.x); pk.s[1] = f2bf(v0.y);
        pk.s[2] = f2bf(v0.z); pk.s[3] = f2bf(v0.w);
        pk.s[4] = f2bf(v1.x); pk.s[5] = f2bf(v1.y);
        pk.s[6] = f2bf(v1.z); pk.s[7] = f2bf(v1.w);
        size_t gr = ((size_t)(r >> 4) * 4 + (g >> 2)) * 64 + (r & 15) + ((g & 3) << 4);
        ((short8*)xdsw)[gr] = pk.v;
    } else {
        // granule ((r>>4)*8 + kc)*64 + (r&15) + 16*sub  (r = out-row)
        int t = (b - PREP_SRC_BLOCKS - PREP_DST_BLOCKS) * 256 + threadIdx.x;
        int r = t >> 5;
        int g = t & 31;
        const float4* p = (const float4*)(W + (size_t)r * 256 + g * 8);
        float4 v0 = p[0], v1 = p[1];
        union { unsigned short s[8]; short8 v; } pk;
        pk.s[0] = f2bf(v0.x); pk.s[1] = f2bf(v0.y);
        pk.s[2] = f2bf(v0.z); pk.s[3] = f2bf(v0.w);
        pk.s[4] = f2bf(v1.x); pk.s[5] = f2bf(v1.y);
        pk.s[6] = f2bf(v1.z); pk.s[7] = f2bf(v1.w);
        size_t gr = ((size_t)(r >> 4) * 8 + (g >> 2)) * 64 + (r & 15) + ((g & 3) << 4);
        ((short8*)wsw)[gr] = pk.v;
    }
}

// ---------------------------------------------------------------------------
// Gather helper macros (quad of nodes; grp = lane>>4 row-slot,
// gcol = lane&15 16B chunk). Proven in rounds 4/6.
// ---------------------------------------------------------------------------
#define G_ISSUE8(U, V, B, I0, I1, I2, I3, N0, N1, N2, N3)                     \
    {                                                                         \
        int r_ = (B) + grp;                                                   \
        { bool v_ = r_ < N0; V[0] = v_; int s_ = __shfl(I0, r_);              \
          s_ = v_ ? s_ : 0;                                                   \
          U[0] = *(const uint4v*)(xsb + (size_t)s_ * D_SRC + gcol * 8); }     \
        { bool v_ = r_ < N1; V[1] = v_; int s_ = __shfl(I1, r_);              \
          s_ = v_ ? s_ : 0;                                                   \
          U[1] = *(const uint4v*)(xsb + (size_t)s_ * D_SRC + gcol * 8); }     \
        { bool v_ = r_ < N2; V[2] = v_; int s_ = __shfl(I2, r_);              \
          s_ = v_ ? s_ : 0;                                                   \
          U[2] = *(const uint4v*)(xsb + (size_t)s_ * D_SRC + gcol * 8); }     \
        { bool v_ = r_ < N3; V[3] = v_; int s_ = __shfl(I3, r_);              \
          s_ = v_ ? s_ : 0;                                                   \
          U[3] = *(const uint4v*)(xsb + (size_t)s_ * D_SRC + gcol * 8); }     \
    }

#define G_ACC1(ACC, W)                                                       \
    ACC[0] += bf_lo(W[0]); ACC[1] += bf_hi(W[0]);                            \
    ACC[2] += bf_lo(W[1]); ACC[3] += bf_hi(W[1]);                            \
    ACC[4] += bf_lo(W[2]); ACC[5] += bf_hi(W[2]);                            \
    ACC[6] += bf_lo(W[3]); ACC[7] += bf_hi(W[3]);

#define G_ACCUM8(U, V, A0, A1, A2, A3)                                       \
    if (V[0]) { G_ACC1(A0, U[0]) }                                           \
    if (V[1]) { G_ACC1(A1, U[1]) }                                           \
    if (V[2]) { G_ACC1(A2, U[2]) }                                           \
    if (V[3]) { G_ACC1(A3, U[3]) }

// ---------------------------------------------------------------------------
// Kernel 2: gather-sum + mean, 8 NODES PER WAVE (2 interleaved quads).
// (Round-6 proven version, unchanged.)
// ---------------------------------------------------------------------------
__global__ __launch_bounds__(256) void gather_kernel(
    const unsigned short* __restrict__ xsb,  // [N, 128] bf16 linear
    const int*   __restrict__ deg,      // [N]
    const int*   __restrict__ bucket,   // [N*CAP]
    const int*   __restrict__ ovf_cnt,  // [1]
    const int*   __restrict__ ovf,      // [OVF_CAP*2]
    unsigned int* __restrict__ aggsw)   // fragment-order bf16 mean (dwords)
{
    int wid  = threadIdx.x >> 6;
    int lane = threadIdx.x & 63;
    int wbase = (blockIdx.x * 4 + wid) * 8;   // 32 nodes/block; 3125 blocks exact
    int grp  = lane >> 4;                     // 0..3
    int gcol = lane & 15;                     // 16B chunk within row

    // degrees for the 8 nodes
    int dl = deg[wbase + (lane & 7)];
    int dtA0 = __shfl(dl, 0), dtA1 = __shfl(dl, 1);
    int dtA2 = __shfl(dl, 2), dtA3 = __shfl(dl, 3);
    int dtB0 = __shfl(dl, 4), dtB1 = __shfl(dl, 5);
    int dtB2 = __shfl(dl, 6), dtB3 = __shfl(dl, 7);
    int nA0 = min(dtA0, CAP), nA1 = min(dtA1, CAP);
    int nA2 = min(dtA2, CAP), nA3 = min(dtA3, CAP);
    int nB0 = min(dtB0, CAP), nB1 = min(dtB1, CAP);
    int nB2 = min(dtB2, CAP), nB3 = min(dtB3, CAP);

    // bucket rows (8 x 128B, sequential 1KB per wave)
    int iA0 = bucket[(size_t)(wbase + 0) * CAP + (lane & 31)];
    int iA1 = bucket[(size_t)(wbase + 1) * CAP + (lane & 31)];
    int iA2 = bucket[(size_t)(wbase + 2) * CAP + (lane & 31)];
    int iA3 = bucket[(size_t)(wbase + 3) * CAP + (lane & 31)];
    int iB0 = bucket[(size_t)(wbase + 4) * CAP + (lane & 31)];
    int iB1 = bucket[(size_t)(wbase + 5) * CAP + (lane & 31)];
    int iB2 = bucket[(size_t)(wbase + 6) * CAP + (lane & 31)];
    int iB3 = bucket[(size_t)(wbase + 7) * CAP + (lane & 31)];

    float accA0[8] = {0,0,0,0,0,0,0,0}, accA1[8] = {0,0,0,0,0,0,0,0};
    float accA2[8] = {0,0,0,0,0,0,0,0}, accA3[8] = {0,0,0,0,0,0,0,0};
    float accB0[8] = {0,0,0,0,0,0,0,0}, accB1[8] = {0,0,0,0,0,0,0,0};
    float accB2[8] = {0,0,0,0,0,0,0,0}, accB3[8] = {0,0,0,0,0,0,0,0};

    int maxn = max(max(max(nA0, nA1), max(nA2, nA3)),
                   max(max(nB0, nB1), max(nB2, nB3)));

    uint4v uAa[4], uAb[4], uBa[4], uBb[4];
    bool   vAa[4], vAb[4], vBa[4], vBb[4];
    if (maxn > 0) {
        G_ISSUE8(uAa, vAa, 0, iA0, iA1, iA2, iA3, nA0, nA1, nA2, nA3)
        G_ISSUE8(uBa, vBa, 0, iB0, iB1, iB2, iB3, nB0, nB1, nB2, nB3)
        int bb = 0;
        while (true) {
            if (bb + 4 < maxn) {
                G_ISSUE8(uAb, vAb, bb + 4, iA0, iA1, iA2, iA3, nA0, nA1, nA2, nA3)
                G_ISSUE8(uBb, vBb, bb + 4, iB0, iB1, iB2, iB3, nB0, nB1, nB2, nB3)
            }
            G_ACCUM8(uAa, vAa, accA0, accA1, accA2, accA3)
            G_ACCUM8(uBa, vBa, accB0, accB1, accB2, accB3)
            bb += 4;
            if (bb >= maxn) break;
            if (bb + 4 < maxn) {
                G_ISSUE8(uAa, vAa, bb + 4, iA0, iA1, iA2, iA3, nA0, nA1, nA2, nA3)
                G_ISSUE8(uBa, vBa, bb + 4, iB0, iB1, iB2, iB3, nB0, nB1, nB2, nB3)
            }
            G_ACCUM8(uAb, vAb, accA0, accA1, accA2, accA3)
            G_ACCUM8(uBb, vBb, accB0, accB1, accB2, accB3)
            bb += 4;
            if (bb >= maxn) break;
        }
    }

    // overflow fallback (astronomically rare)
    if ((dtA0 > CAP) | (dtA1 > CAP) | (dtA2 > CAP) | (dtA3 > CAP) |
        (dtB0 > CAP) | (dtB1 > CAP) | (dtB2 > CAP) | (dtB3 > CAP)) {
        int oc = *ovf_cnt;
        if (oc > OVF_CAP) oc = OVF_CAP;
        for (int o = 0; o < oc; ++o) {
            int od  = ovf[2 * o + 1];
            int rel = od - wbase;
            if (rel >= 0 && rel < 8) {
                int s0 = ovf[2 * o];
                uint4v w = *(const uint4v*)(xsb + (size_t)s0 * D_SRC + gcol * 8);
                if (grp == 0) {   // add once; butterfly distributes it
                    if      (rel == 0) { G_ACC1(accA0, w) }
                    else if (rel == 1) { G_ACC1(accA1, w) }
                    else if (rel == 2) { G_ACC1(accA2, w) }
                    else if (rel == 3) { G_ACC1(accA3, w) }
                    else if (rel == 4) { G_ACC1(accB0, w) }
                    else if (rel == 5) { G_ACC1(accB1, w) }
                    else if (rel == 6) { G_ACC1(accB2, w) }
                    else               { G_ACC1(accB3, w) }
                }
            }
        }
    }

    // butterfly-reduce across the 4 row-groups (lanes ^16, ^32)
    #pragma unroll
    for (int k = 0; k < 8; ++k) {
        accA0[k] += __shfl_xor(accA0[k], 16); accA0[k] += __shfl_xor(accA0[k], 32);
        accA1[k] += __shfl_xor(accA1[k], 16); accA1[k] += __shfl_xor(accA1[k], 32);
        accA2[k] += __shfl_xor(accA2[k], 16); accA2[k] += __shfl_xor(accA2[k], 32);
        accA3[k] += __shfl_xor(accA3[k], 16); accA3[k] += __shfl_xor(accA3[k], 32);
        accB0[k] += __shfl_xor(accB0[k], 16); accB0[k] += __shfl_xor(accB0[k], 32);
        accB1[k] += __shfl_xor(accB1[k], 16); accB1[k] += __shfl_xor(accB1[k], 32);
        accB2[k] += __shfl_xor(accB2[k], 16); accB2[k] += __shfl_xor(accB2[k], 32);
        accB3[k] += __shfl_xor(accB3[k], 16); accB3[k] += __shfl_xor(accB3[k], 32);
    }

    // quad A: lane (grp, gcol) stores granule gcol of node wbase+grp
    {
        int dsel = dtA0;
        dsel = (grp == 1) ? dtA1 : dsel;
        dsel = (grp == 2) ? dtA2 : dsel;
        dsel = (grp == 3) ? dtA3 : dsel;
        float inv = 1.0f / (float)((dsel > 1) ? dsel : 1);
        float sum[8];
        #pragma unroll
        for (int k = 0; k < 8; ++k) {
            float v = accA0[k];
            v = (grp == 1) ? accA1[k] : v;
            v = (grp == 2) ? accA2[k] : v;
            v = (grp == 3) ? accA3[k] : v;
            sum[k] = v * inv;
        }
        uint4v o;
        o[0] = (unsigned)f2bf(sum[0]) | ((unsigned)f2bf(sum[1]) << 16);
        o[1] = (unsigned)f2bf(sum[2]) | ((unsigned)f2bf(sum[3]) << 16);
        o[2] = (unsigned)f2bf(sum[4]) | ((unsigned)f2bf(sum[5]) << 16);
        o[3] = (unsigned)f2bf(sum[6]) | ((unsigned)f2bf(sum[7]) << 16);
        int node = wbase + grp;
        size_t gr = ((size_t)(node >> 4) * 4 + (gcol >> 2)) * 64
                  + (node & 15) + ((gcol & 3) << 4);
        ((uint4v*)aggsw)[gr] = o;
    }
    // quad B: node wbase+4+grp
    {
        int dsel = dtB0;
        dsel = (grp == 1) ? dtB1 : dsel;
        dsel = (grp == 2) ? dtB2 : dsel;
        dsel = (grp == 3) ? dtB3 : dsel;
        float inv = 1.0f / (float)((dsel > 1) ? dsel : 1);
        float sum[8];
        #pragma unroll
        for (int k = 0; k < 8; ++k) {
            float v = accB0[k];
            v = (grp == 1) ? accB1[k] : v;
            v = (grp == 2) ? accB2[k] : v;
            v = (grp == 3) ? accB3[k] : v;
            sum[k] = v * inv;
        }
        uint4v o;
        o[0] = (unsigned)f2bf(sum[0]) | ((unsigned)f2bf(sum[1]) << 16);
        o[1] = (unsigned)f2bf(sum[2]) | ((unsigned)f2bf(sum[3]) << 16);
        o[2] = (unsigned)f2bf(sum[4]) | ((unsigned)f2bf(sum[5]) << 16);
        o[3] = (unsigned)f2bf(sum[6]) | ((unsigned)f2bf(sum[7]) << 16);
        int node = wbase + 4 + grp;
        size_t gr = ((size_t)(node >> 4) * 4 + (gcol >> 2)) * 64
                  + (node & 15) + ((gcol & 3) << 4);
        ((uint4v*)aggsw)[gr] = o;
    }
}

// ---------------------------------------------------------------------------
// Kernel 3: MFMA GEMM (round-4/6 proven version, unchanged).
// ---------------------------------------------------------------------------
__global__ __launch_bounds__(256) void mfma_gemm_kernel(
    const short8* __restrict__ xdsw,   // [N/16][4][64] granules
    const short8* __restrict__ aggsw,  // [N/16][4][64] granules
    const short8* __restrict__ wsw,    // [16][8][64] granules
    const float* __restrict__ bias,    // [256]
    float*       __restrict__ out)     // [N, 256] fp32
{
    __shared__ float eps[4][16][68];   // [wave][row][col64 + pad4]

    int wave = threadIdx.x >> 6;  // column block n0 = wave*64
    int lane = threadIdx.x & 63;
    int lrow = lane & 15;
    int kq   = lane >> 4;
    int mb   = blockIdx.x;        // 64-row tile
    int m0   = mb * 64;
    int n0   = wave * 64;

    bool mok[4];
    #pragma unroll
    for (int mf = 0; mf < 4; ++mf) mok[mf] = (m0 + mf * 16) < N_NODES;

    const short8* Ax = xdsw  + (size_t)mb * 1024 + lane;   // + mf*256 + kc*64
    const short8* Ag = aggsw + (size_t)mb * 1024 + lane;   // + mf*256 + kc'*64
    const short8* Bw = wsw   + (size_t)wave * 2048 + lane; // + nf*512 + kc*64

    float4v acc[4][4];
    #pragma unroll
    for (int i = 0; i < 4; ++i)
        #pragma unroll
        for (int j = 0; j < 4; ++j)
            acc[i][j] = (float4v){0.f, 0.f, 0.f, 0.f};

    const short8 zfrag = (short8){0,0,0,0,0,0,0,0};
    short8 a[2][4], b[2][4];

    #pragma unroll
    for (int mf = 0; mf < 4; ++mf)
        a[0][mf] = mok[mf] ? Ax[mf * 256] : zfrag;
    #pragma unroll
    for (int nf = 0; nf < 4; ++nf)
        b[0][nf] = Bw[nf * 512];

    #pragma unroll
    for (int kc = 0; kc < 8; ++kc) {
        const int cur = kc & 1, nxt = cur ^ 1;
        if (kc < 7) {
            const int k1 = kc + 1;
            const short8* A = (k1 < 4) ? Ax : Ag;
            const int kk = (k1 < 4) ? k1 : (k1 - 4);
            #pragma unroll
            for (int mf = 0; mf < 4; ++mf)
                a[nxt][mf] = mok[mf] ? A[mf * 256 + kk * 64] : zfrag;
            #pragma unroll
            for (int nf = 0; nf < 4; ++nf)
                b[nxt][nf] = Bw[nf * 512 + k1 * 64];
        }
        #pragma unroll
        for (int mf = 0; mf < 4; ++mf)
            #pragma unroll
            for (int nf = 0; nf < 4; ++nf)
                acc[mf][nf] = __builtin_amdgcn_mfma_f32_16x16x32_bf16(
                    a[cur][mf], b[cur][nf], acc[mf][nf], 0, 0, 0);
    }

    // ---- epilogue: bias+relu, wave-private LDS bounce, 256B nt stores ----
    float bv[4];
    #pragma unroll
    for (int nf = 0; nf < 4; ++nf)
        bv[nf] = bias[n0 + nf * 16 + lrow];

    int srow   = lane >> 4;     // 0..3
    int schunk = lane & 15;     // 16B units across 64 cols

    #pragma unroll
    for (int mf = 0; mf < 4; ++mf) {
        if (!mok[mf]) continue;   // block-uniform
        #pragma unroll
        for (int nf = 0; nf < 4; ++nf)
            #pragma unroll
            for (int r = 0; r < 4; ++r)
                eps[wave][kq * 4 + r][nf * 16 + lrow] =
                    fmaxf(acc[mf][nf][r] + bv[nf], 0.f);
        asm volatile("s_waitcnt lgkmcnt(0)" ::: "memory");
        #pragma unroll
        for (int c = 0; c < 4; ++c) {
            int row  = c * 4 + srow;
            float4v v = *(const float4v*)&eps[wave][row][schunk * 4];
            int grow = m0 + mf * 16 + row;
            __builtin_nontemporal_store(v,
                (float4v*)(out + (size_t)grow * D_OUT + n0 + schunk * 4));
        }
        asm volatile("s_waitcnt lgkmcnt(0)" ::: "memory");
    }
}

extern "C" void kernel_launch(void* const* d_in, const int* in_sizes, int n_in,
                              void* d_out, int out_size, void* d_ws, size_t ws_size,
                              hipStream_t stream) {
    const float* x_src = (const float*)d_in[0];
    const float* x_dst = (const float*)d_in[1];
    const int*   ei    = (const int*)d_in[2];
    const float* W     = (const float*)d_in[3];
    const float* bias  = (const float*)d_in[4];
    float* out = (float*)d_out;

    int n_edges = in_sizes[2] / 2;

    // workspace layout (ws):
    //   deg    : N_NODES int           (zeroed by memset)
    //   ovf_cnt: 4 int                 (zeroed by memset)
    //   ovf    : OVF_CAP*2 int
    //   wsw    : 256*256 ushort  (bf16 W, fragment order)
    //   aggsw  : N/16*4*64*8 ushort (bf16 agg, fragment order)
    //   xdsw   : N/16*4*64*8 ushort (bf16 x_dst, fragment order)
    int* deg     = (int*)d_ws;
    int* ovf_cnt = deg + N_NODES;
    int* ovf     = ovf_cnt + 4;
    unsigned short* wsw   = (unsigned short*)(ovf + OVF_CAP * 2);
    unsigned short* aggsw = wsw + (size_t)D_OUT * K_DIM;
    unsigned short* xdsw  = aggsw + (size_t)(N_NODES / 16) * 4 * 64 * 8;

    // d_out doubles as stream-ordered scratch for buffers dead before GEMM:
    //   bucket : N_NODES*CAP int   at offset 0        (12.8 MB)
    //   xsb    : N_NODES*128 ushort at 12.8 MB        (25.6 MB)
    int* bucket = (int*)d_out;
    unsigned short* xsb = (unsigned short*)(bucket + (size_t)N_NODES * CAP);

    hipMemsetAsync(d_ws, 0, (N_NODES + 4) * sizeof(int), stream);

    int nb_bucket = (n_edges + 255) / 256;
    int prep_blocks = nb_bucket + PREP_SRC_BLOCKS + PREP_DST_BLOCKS + PREP_W_BLOCKS;
    prep_kernel<<<prep_blocks, 256, 0, stream>>>(
        x_src, x_dst, W, ei, xsb, xdsw, wsw,
        deg, ovf_cnt, ovf, bucket, n_edges, nb_bucket);

    gather_kernel<<<(N_NODES + 31) / 32, 256, 0, stream>>>(
        xsb, deg, bucket, ovf_cnt, ovf, (unsigned int*)aggsw);

    mfma_gemm_kernel<<<(N_NODES + 63) / 64, 256, 0, stream>>>(
        (const short8*)xdsw, (const short8*)aggsw, (const short8*)wsw, bias, out);
}

// Round 9
// 276.858 us; speedup vs baseline: 1.0400x; 1.0400x over previous
//
#include <hip/hip_runtime.h>

#define N_NODES 100000
#define D_SRC 128
#define D_OUT 256
#define K_DIM 256   // D_DST + D_SRC
#define ROW 32      // bucket row: [count | 31 slots] = 128B, one cache-line pair
#define SLOTS 31    // P(deg>31) Poisson(6) ~ 1e-15
#define OVF_CAP 2048

typedef __attribute__((ext_vector_type(8))) short short8;
typedef __attribute__((ext_vector_type(4))) float float4v;
typedef __attribute__((ext_vector_type(4))) unsigned int uint4v;

__device__ inline unsigned short f2bf(float f) {
    unsigned int u = __float_as_uint(f);
    u += 0x7FFF + ((u >> 16) & 1);   // round-to-nearest-even
    return (unsigned short)(u >> 16);
}
__device__ inline float bf_lo(unsigned int u) { return __uint_as_float(u << 16); }
__device__ inline float bf_hi(unsigned int u) { return __uint_as_float(u & 0xFFFF0000u); }

// ---------------------------------------------------------------------------
// Kernel 1 (bucket + pack_src): bucket blocks first, pack_src backfills.
// Bucket v3: count lives at bucket[d*32]; slots at bucket[d*32+1+pos].
// The atomicAdd and the slot store hit the SAME 128B row (same 64B line for
// pos<15, 99.97% of edges) -> halves distinct-line transactions vs separate
// deg[] + bucket[] (round-8 evidence: transaction-rate-bound, ~4/cycle).
// ---------------------------------------------------------------------------
#define PREP_SRC_BLOCKS 12500              // N*128/4 float4 / 256

__global__ __launch_bounds__(256) void k_bucket_src(
    const int*   __restrict__ ei,      // [2, E]
    const float* __restrict__ x_src,
    int* __restrict__ bucket,          // [N*32], counts pre-zeroed
    int* __restrict__ ovf_cnt,         // [1], pre-zeroed
    int* __restrict__ ovf,             // [OVF_CAP*2]
    unsigned short* __restrict__ xsb,  // [N,128] bf16
    int n_edges, int nb_bucket)
{
    int b = blockIdx.x;
    if (b < nb_bucket) {
        int e = b * 256 + threadIdx.x;
        if (e < n_edges) {
            int s = ei[e];
            int d = ei[n_edges + e];
            int pos = atomicAdd(bucket + (size_t)d * ROW, 1);
            if (pos < SLOTS) {
                bucket[(size_t)d * ROW + 1 + pos] = s;   // same line as count
            } else {
                int o = atomicAdd(ovf_cnt, 1);
                if (o < OVF_CAP) { ovf[2 * o] = s; ovf[2 * o + 1] = d; }
            }
        }
        return;
    }
    // ---- pack_src: one float4 -> ushort4 per thread, grid exact ----
    int i = (b - nb_bucket) * 256 + threadIdx.x;
    float4 v = ((const float4*)x_src)[i];
    ushort4 o;
    o.x = f2bf(v.x); o.y = f2bf(v.y); o.z = f2bf(v.z); o.w = f2bf(v.w);
    ((ushort4*)xsb)[i] = o;
}

// ---------------------------------------------------------------------------
// Gather helper macros. Row register I holds bucket[node*32 + (lane&31)]:
// element 0 = count, elements 1..31 = slots -> slot r is __shfl(I, 1+r).
// ---------------------------------------------------------------------------
#define G_ISSUE8(U, V, B, I0, I1, I2, I3, N0, N1, N2, N3)                     \
    {                                                                         \
        int r_ = (B) + grp;                                                   \
        { bool v_ = r_ < N0; V[0] = v_; int s_ = __shfl(I0, 1 + r_);          \
          s_ = v_ ? s_ : 0;                                                   \
          U[0] = *(const uint4v*)(xsb + (size_t)s_ * D_SRC + gcol * 8); }     \
        { bool v_ = r_ < N1; V[1] = v_; int s_ = __shfl(I1, 1 + r_);          \
          s_ = v_ ? s_ : 0;                                                   \
          U[1] = *(const uint4v*)(xsb + (size_t)s_ * D_SRC + gcol * 8); }     \
        { bool v_ = r_ < N2; V[2] = v_; int s_ = __shfl(I2, 1 + r_);          \
          s_ = v_ ? s_ : 0;                                                   \
          U[2] = *(const uint4v*)(xsb + (size_t)s_ * D_SRC + gcol * 8); }     \
        { bool v_ = r_ < N3; V[3] = v_; int s_ = __shfl(I3, 1 + r_);          \
          s_ = v_ ? s_ : 0;                                                   \
          U[3] = *(const uint4v*)(xsb + (size_t)s_ * D_SRC + gcol * 8); }     \
    }

#define G_ACC1(ACC, W)                                                       \
    ACC[0] += bf_lo(W[0]); ACC[1] += bf_hi(W[0]);                            \
    ACC[2] += bf_lo(W[1]); ACC[3] += bf_hi(W[1]);                            \
    ACC[4] += bf_lo(W[2]); ACC[5] += bf_hi(W[2]);                            \
    ACC[6] += bf_lo(W[3]); ACC[7] += bf_hi(W[3]);

#define G_ACCUM8(U, V, A0, A1, A2, A3)                                       \
    if (V[0]) { G_ACC1(A0, U[0]) }                                           \
    if (V[1]) { G_ACC1(A1, U[1]) }                                           \
    if (V[2]) { G_ACC1(A2, U[2]) }                                           \
    if (V[3]) { G_ACC1(A3, U[3]) }

// ---------------------------------------------------------------------------
// Kernel 2 (gather + pack_dst + pack_w): gather blocks [0,3125) first
// (latency-bound, start early); streaming pack blocks backfill.
// Gather: 8 nodes/wave, 2 interleaved double-buffered quads (round-6 proven);
// deg reads are gone — count rides in the bucket row.
// ---------------------------------------------------------------------------
#define GATHER_BLOCKS 3125                 // N/32 exact
#define PREP_DST_BLOCKS 6250               // N*16 threads / 256
#define PREP_W_BLOCKS   32                 // 256*256/8 / 256

__global__ __launch_bounds__(256) void k_gather_pack(
    const unsigned short* __restrict__ xsb,  // [N, 128] bf16 linear
    const int*   __restrict__ bucket,   // [N*32] rows (count|slots)
    const int*   __restrict__ ovf_cnt,  // [1]
    const int*   __restrict__ ovf,      // [OVF_CAP*2]
    unsigned int* __restrict__ aggsw,   // fragment-order bf16 mean (dwords)
    const float* __restrict__ x_dst,
    const float* __restrict__ W,
    unsigned short* __restrict__ xdsw,
    unsigned short* __restrict__ wsw)
{
    int blk = blockIdx.x;
    if (blk >= GATHER_BLOCKS) {
        int pb = blk - GATHER_BLOCKS;
        if (pb < PREP_DST_BLOCKS) {
            // granule ((r>>4)*4 + kc)*64 + (r&15) + 16*sub <- x_dst[r][kc*32+sub*8+j]
            int t = pb * 256 + threadIdx.x;
            int r = t >> 4;
            int g = t & 15;
            const float4* p = (const float4*)(x_dst + (size_t)r * 128 + g * 8);
            float4 v0 = p[0], v1 = p[1];
            union { unsigned short s[8]; short8 v; } pk;
            pk.s[0] = f2bf(v0.x); pk.s[1] = f2bf(v0.y);
            pk.s[2] = f2bf(v0.z); pk.s[3] = f2bf(v0.w);
            pk.s[4] = f2bf(v1.x); pk.s[5] = f2bf(v1.y);
            pk.s[6] = f2bf(v1.z); pk.s[7] = f2bf(v1.w);
            size_t gr = ((size_t)(r >> 4) * 4 + (g >> 2)) * 64 + (r & 15) + ((g & 3) << 4);
            ((short8*)xdsw)[gr] = pk.v;
        } else {
            // granule ((r>>4)*8 + kc)*64 + (r&15) + 16*sub  (r = out-row)
            int t = (pb - PREP_DST_BLOCKS) * 256 + threadIdx.x;
            int r = t >> 5;
            int g = t & 31;
            const float4* p = (const float4*)(W + (size_t)r * 256 + g * 8);
            float4 v0 = p[0], v1 = p[1];
            union { unsigned short s[8]; short8 v; } pk;
            pk.s[0] = f2bf(v0.x); pk.s[1] = f2bf(v0.y);
            pk.s[2] = f2bf(v0.z); pk.s[3] = f2bf(v0.w);
            pk.s[4] = f2bf(v1.x); pk.s[5] = f2bf(v1.y);
            pk.s[6] = f2bf(v1.z); pk.s[7] = f2bf(v1.w);
            size_t gr = ((size_t)(r >> 4) * 8 + (g >> 2)) * 64 + (r & 15) + ((g & 3) << 4);
            ((short8*)wsw)[gr] = pk.v;
        }
        return;
    }

    int wid  = threadIdx.x >> 6;
    int lane = threadIdx.x & 63;
    int wbase = (blk * 4 + wid) * 8;          // 32 nodes/block; 3125 blocks exact
    int grp  = lane >> 4;                     // 0..3
    int gcol = lane & 15;                     // 16B chunk within row

    // bucket rows (8 x 128B, sequential 1KB per wave); element0 = count
    int iA0 = bucket[(size_t)(wbase + 0) * ROW + (lane & 31)];
    int iA1 = bucket[(size_t)(wbase + 1) * ROW + (lane & 31)];
    int iA2 = bucket[(size_t)(wbase + 2) * ROW + (lane & 31)];
    int iA3 = bucket[(size_t)(wbase + 3) * ROW + (lane & 31)];
    int iB0 = bucket[(size_t)(wbase + 4) * ROW + (lane & 31)];
    int iB1 = bucket[(size_t)(wbase + 5) * ROW + (lane & 31)];
    int iB2 = bucket[(size_t)(wbase + 6) * ROW + (lane & 31)];
    int iB3 = bucket[(size_t)(wbase + 7) * ROW + (lane & 31)];

    int dtA0 = __shfl(iA0, 0), dtA1 = __shfl(iA1, 0);
    int dtA2 = __shfl(iA2, 0), dtA3 = __shfl(iA3, 0);
    int dtB0 = __shfl(iB0, 0), dtB1 = __shfl(iB1, 0);
    int dtB2 = __shfl(iB2, 0), dtB3 = __shfl(iB3, 0);
    int nA0 = min(dtA0, SLOTS), nA1 = min(dtA1, SLOTS);
    int nA2 = min(dtA2, SLOTS), nA3 = min(dtA3, SLOTS);
    int nB0 = min(dtB0, SLOTS), nB1 = min(dtB1, SLOTS);
    int nB2 = min(dtB2, SLOTS), nB3 = min(dtB3, SLOTS);

    float accA0[8] = {0,0,0,0,0,0,0,0}, accA1[8] = {0,0,0,0,0,0,0,0};
    float accA2[8] = {0,0,0,0,0,0,0,0}, accA3[8] = {0,0,0,0,0,0,0,0};
    float accB0[8] = {0,0,0,0,0,0,0,0}, accB1[8] = {0,0,0,0,0,0,0,0};
    float accB2[8] = {0,0,0,0,0,0,0,0}, accB3[8] = {0,0,0,0,0,0,0,0};

    int maxn = max(max(max(nA0, nA1), max(nA2, nA3)),
                   max(max(nB0, nB1), max(nB2, nB3)));

    uint4v uAa[4], uAb[4], uBa[4], uBb[4];
    bool   vAa[4], vAb[4], vBa[4], vBb[4];
    if (maxn > 0) {
        G_ISSUE8(uAa, vAa, 0, iA0, iA1, iA2, iA3, nA0, nA1, nA2, nA3)
        G_ISSUE8(uBa, vBa, 0, iB0, iB1, iB2, iB3, nB0, nB1, nB2, nB3)
        int bb = 0;
        while (true) {
            if (bb + 4 < maxn) {
                G_ISSUE8(uAb, vAb, bb + 4, iA0, iA1, iA2, iA3, nA0, nA1, nA2, nA3)
                G_ISSUE8(uBb, vBb, bb + 4, iB0, iB1, iB2, iB3, nB0, nB1, nB2, nB3)
            }
            G_ACCUM8(uAa, vAa, accA0, accA1, accA2, accA3)
            G_ACCUM8(uBa, vBa, accB0, accB1, accB2, accB3)
            bb += 4;
            if (bb >= maxn) break;
            if (bb + 4 < maxn) {
                G_ISSUE8(uAa, vAa, bb + 4, iA0, iA1, iA2, iA3, nA0, nA1, nA2, nA3)
                G_ISSUE8(uBa, vBa, bb + 4, iB0, iB1, iB2, iB3, nB0, nB1, nB2, nB3)
            }
            G_ACCUM8(uAb, vAb, accA0, accA1, accA2, accA3)
            G_ACCUM8(uBb, vBb, accB0, accB1, accB2, accB3)
            bb += 4;
            if (bb >= maxn) break;
        }
    }

    // overflow fallback (astronomically rare)
    if ((dtA0 > SLOTS) | (dtA1 > SLOTS) | (dtA2 > SLOTS) | (dtA3 > SLOTS) |
        (dtB0 > SLOTS) | (dtB1 > SLOTS) | (dtB2 > SLOTS) | (dtB3 > SLOTS)) {
        int oc = *ovf_cnt;
        if (oc > OVF_CAP) oc = OVF_CAP;
        for (int o = 0; o < oc; ++o) {
            int od  = ovf[2 * o + 1];
            int rel = od - wbase;
            if (rel >= 0 && rel < 8) {
                int s0 = ovf[2 * o];
                uint4v w = *(const uint4v*)(xsb + (size_t)s0 * D_SRC + gcol * 8);
                if (grp == 0) {   // add once; butterfly distributes it
                    if      (rel == 0) { G_ACC1(accA0, w) }
                    else if (rel == 1) { G_ACC1(accA1, w) }
                    else if (rel == 2) { G_ACC1(accA2, w) }
                    else if (rel == 3) { G_ACC1(accA3, w) }
                    else if (rel == 4) { G_ACC1(accB0, w) }
                    else if (rel == 5) { G_ACC1(accB1, w) }
                    else if (rel == 6) { G_ACC1(accB2, w) }
                    else               { G_ACC1(accB3, w) }
                }
            }
        }
    }

    // butterfly-reduce across the 4 row-groups (lanes ^16, ^32)
    #pragma unroll
    for (int k = 0; k < 8; ++k) {
        accA0[k] += __shfl_xor(accA0[k], 16); accA0[k] += __shfl_xor(accA0[k], 32);
        accA1[k] += __shfl_xor(accA1[k], 16); accA1[k] += __shfl_xor(accA1[k], 32);
        accA2[k] += __shfl_xor(accA2[k], 16); accA2[k] += __shfl_xor(accA2[k], 32);
        accA3[k] += __shfl_xor(accA3[k], 16); accA3[k] += __shfl_xor(accA3[k], 32);
        accB0[k] += __shfl_xor(accB0[k], 16); accB0[k] += __shfl_xor(accB0[k], 32);
        accB1[k] += __shfl_xor(accB1[k], 16); accB1[k] += __shfl_xor(accB1[k], 32);
        accB2[k] += __shfl_xor(accB2[k], 16); accB2[k] += __shfl_xor(accB2[k], 32);
        accB3[k] += __shfl_xor(accB3[k], 16); accB3[k] += __shfl_xor(accB3[k], 32);
    }

    // quad A: lane (grp, gcol) stores granule gcol of node wbase+grp
    {
        int dsel = dtA0;
        dsel = (grp == 1) ? dtA1 : dsel;
        dsel = (grp == 2) ? dtA2 : dsel;
        dsel = (grp == 3) ? dtA3 : dsel;
        float inv = 1.0f / (float)((dsel > 1) ? dsel : 1);
        float sum[8];
        #pragma unroll
        for (int k = 0; k < 8; ++k) {
            float v = accA0[k];
            v = (grp == 1) ? accA1[k] : v;
            v = (grp == 2) ? accA2[k] : v;
            v = (grp == 3) ? accA3[k] : v;
            sum[k] = v * inv;
        }
        uint4v o;
        o[0] = (unsigned)f2bf(sum[0]) | ((unsigned)f2bf(sum[1]) << 16);
        o[1] = (unsigned)f2bf(sum[2]) | ((unsigned)f2bf(sum[3]) << 16);
        o[2] = (unsigned)f2bf(sum[4]) | ((unsigned)f2bf(sum[5]) << 16);
        o[3] = (unsigned)f2bf(sum[6]) | ((unsigned)f2bf(sum[7]) << 16);
        int node = wbase + grp;
        size_t gr = ((size_t)(node >> 4) * 4 + (gcol >> 2)) * 64
                  + (node & 15) + ((gcol & 3) << 4);
        ((uint4v*)aggsw)[gr] = o;
    }
    // quad B: node wbase+4+grp
    {
        int dsel = dtB0;
        dsel = (grp == 1) ? dtB1 : dsel;
        dsel = (grp == 2) ? dtB2 : dsel;
        dsel = (grp == 3) ? dtB3 : dsel;
        float inv = 1.0f / (float)((dsel > 1) ? dsel : 1);
        float sum[8];
        #pragma unroll
        for (int k = 0; k < 8; ++k) {
            float v = accB0[k];
            v = (grp == 1) ? accB1[k] : v;
            v = (grp == 2) ? accB2[k] : v;
            v = (grp == 3) ? accB3[k] : v;
            sum[k] = v * inv;
        }
        uint4v o;
        o[0] = (unsigned)f2bf(sum[0]) | ((unsigned)f2bf(sum[1]) << 16);
        o[1] = (unsigned)f2bf(sum[2]) | ((unsigned)f2bf(sum[3]) << 16);
        o[2] = (unsigned)f2bf(sum[4]) | ((unsigned)f2bf(sum[5]) << 16);
        o[3] = (unsigned)f2bf(sum[6]) | ((unsigned)f2bf(sum[7]) << 16);
        int node = wbase + 4 + grp;
        size_t gr = ((size_t)(node >> 4) * 4 + (gcol >> 2)) * 64
                  + (node & 15) + ((gcol & 3) << 4);
        ((uint4v*)aggsw)[gr] = o;
    }
}

// ---------------------------------------------------------------------------
// Kernel 3: MFMA GEMM (round-4/6 proven version, unchanged).
// ---------------------------------------------------------------------------
__global__ __launch_bounds__(256) void mfma_gemm_kernel(
    const short8* __restrict__ xdsw,   // [N/16][4][64] granules
    const short8* __restrict__ aggsw,  // [N/16][4][64] granules
    const short8* __restrict__ wsw,    // [16][8][64] granules
    const float* __restrict__ bias,    // [256]
    float*       __restrict__ out)     // [N, 256] fp32
{
    __shared__ float eps[4][16][68];   // [wave][row][col64 + pad4]

    int wave = threadIdx.x >> 6;  // column block n0 = wave*64
    int lane = threadIdx.x & 63;
    int lrow = lane & 15;
    int kq   = lane >> 4;
    int mb   = blockIdx.x;        // 64-row tile
    int m0   = mb * 64;
    int n0   = wave * 64;

    bool mok[4];
    #pragma unroll
    for (int mf = 0; mf < 4; ++mf) mok[mf] = (m0 + mf * 16) < N_NODES;

    const short8* Ax = xdsw  + (size_t)mb * 1024 + lane;   // + mf*256 + kc*64
    const short8* Ag = aggsw + (size_t)mb * 1024 + lane;   // + mf*256 + kc'*64
    const short8* Bw = wsw   + (size_t)wave * 2048 + lane; // + nf*512 + kc*64

    float4v acc[4][4];
    #pragma unroll
    for (int i = 0; i < 4; ++i)
        #pragma unroll
        for (int j = 0; j < 4; ++j)
            acc[i][j] = (float4v){0.f, 0.f, 0.f, 0.f};

    const short8 zfrag = (short8){0,0,0,0,0,0,0,0};
    short8 a[2][4], b[2][4];

    #pragma unroll
    for (int mf = 0; mf < 4; ++mf)
        a[0][mf] = mok[mf] ? Ax[mf * 256] : zfrag;
    #pragma unroll
    for (int nf = 0; nf < 4; ++nf)
        b[0][nf] = Bw[nf * 512];

    #pragma unroll
    for (int kc = 0; kc < 8; ++kc) {
        const int cur = kc & 1, nxt = cur ^ 1;
        if (kc < 7) {
            const int k1 = kc + 1;
            const short8* A = (k1 < 4) ? Ax : Ag;
            const int kk = (k1 < 4) ? k1 : (k1 - 4);
            #pragma unroll
            for (int mf = 0; mf < 4; ++mf)
                a[nxt][mf] = mok[mf] ? A[mf * 256 + kk * 64] : zfrag;
            #pragma unroll
            for (int nf = 0; nf < 4; ++nf)
                b[nxt][nf] = Bw[nf * 512 + k1 * 64];
        }
        #pragma unroll
        for (int mf = 0; mf < 4; ++mf)
            #pragma unroll
            for (int nf = 0; nf < 4; ++nf)
                acc[mf][nf] = __builtin_amdgcn_mfma_f32_16x16x32_bf16(
                    a[cur][mf], b[cur][nf], acc[mf][nf], 0, 0, 0);
    }

    // ---- epilogue: bias+relu, wave-private LDS bounce, 256B nt stores ----
    float bv[4];
    #pragma unroll
    for (int nf = 0; nf < 4; ++nf)
        bv[nf] = bias[n0 + nf * 16 + lrow];

    int srow   = lane >> 4;     // 0..3
    int schunk = lane & 15;     // 16B units across 64 cols

    #pragma unroll
    for (int mf = 0; mf < 4; ++mf) {
        if (!mok[mf]) continue;   // block-uniform
        #pragma unroll
        for (int nf = 0; nf < 4; ++nf)
            #pragma unroll
            for (int r = 0; r < 4; ++r)
                eps[wave][kq * 4 + r][nf * 16 + lrow] =
                    fmaxf(acc[mf][nf][r] + bv[nf], 0.f);
        asm volatile("s_waitcnt lgkmcnt(0)" ::: "memory");
        #pragma unroll
        for (int c = 0; c < 4; ++c) {
            int row  = c * 4 + srow;
            float4v v = *(const float4v*)&eps[wave][row][schunk * 4];
            int grow = m0 + mf * 16 + row;
            __builtin_nontemporal_store(v,
                (float4v*)(out + (size_t)grow * D_OUT + n0 + schunk * 4));
        }
        asm volatile("s_waitcnt lgkmcnt(0)" ::: "memory");
    }
}

extern "C" void kernel_launch(void* const* d_in, const int* in_sizes, int n_in,
                              void* d_out, int out_size, void* d_ws, size_t ws_size,
                              hipStream_t stream) {
    const float* x_src = (const float*)d_in[0];
    const float* x_dst = (const float*)d_in[1];
    const int*   ei    = (const int*)d_in[2];
    const float* W     = (const float*)d_in[3];
    const float* bias  = (const float*)d_in[4];
    float* out = (float*)d_out;

    int n_edges = in_sizes[2] / 2;

    // workspace layout (ws):
    //   ovf_cnt: 4 int                 (zeroed by memset)
    //   ovf    : OVF_CAP*2 int
    //   wsw    : 256*256 ushort  (bf16 W, fragment order)
    //   aggsw  : N/16*4*64*8 ushort (bf16 agg, fragment order)
    //   xdsw   : N/16*4*64*8 ushort (bf16 x_dst, fragment order)
    int* ovf_cnt = (int*)d_ws;
    int* ovf     = ovf_cnt + 4;
    unsigned short* wsw   = (unsigned short*)(ovf + OVF_CAP * 2);
    unsigned short* aggsw = wsw + (size_t)D_OUT * K_DIM;
    unsigned short* xdsw  = aggsw + (size_t)(N_NODES / 16) * 4 * 64 * 8;

    // d_out doubles as stream-ordered scratch for buffers dead before GEMM:
    //   bucket : N_NODES*32 int (count|slots rows) at offset 0   (12.8 MB)
    //   xsb    : N_NODES*128 ushort at 12.8 MB                   (25.6 MB)
    int* bucket = (int*)d_out;
    unsigned short* xsb = (unsigned short*)(bucket + (size_t)N_NODES * ROW);

    hipMemsetAsync(ovf_cnt, 0, 16, stream);
    hipMemsetAsync(bucket, 0, (size_t)N_NODES * ROW * sizeof(int), stream);

    int nb_bucket = (n_edges + 255) / 256;
    k_bucket_src<<<nb_bucket + PREP_SRC_BLOCKS, 256, 0, stream>>>(
        ei, x_src, bucket, ovf_cnt, ovf, xsb, n_edges, nb_bucket);

    k_gather_pack<<<GATHER_BLOCKS + PREP_DST_BLOCKS + PREP_W_BLOCKS, 256, 0, stream>>>(
        xsb, bucket, ovf_cnt, ovf, (unsigned int*)aggsw, x_dst, W, xdsw, wsw);

    mfma_gemm_kernel<<<(N_NODES + 63) / 64, 256, 0, stream>>>(
        (const short8*)xdsw, (const short8*)aggsw, (const short8*)wsw, bias, out);
}